// Round 1
// 3502.567 us; speedup vs baseline: 1.0005x; 1.0005x over previous
//
#include <hip/hip_runtime.h>

typedef __bf16 bf16;
typedef __bf16 bf16x8 __attribute__((ext_vector_type(8)));
typedef __bf16 bf16x4 __attribute__((ext_vector_type(4)));
typedef float  f32x4  __attribute__((ext_vector_type(4)));

#define NLAYER 6
#define DMODEL 1024
#define NHEAD  16
#define DHEAD  64
#define FFDIM  4096
#define BATCH  8
#define SEQLEN 512
#define MTOK   (BATCH * SEQLEN)   // 4096 tokens
#define QKVLD  3072               // fused q|k|v row stride

#define GAS(p) ((const __attribute__((address_space(1))) void*)(p))
#define LAS(p) ((__attribute__((address_space(3))) void*)(p))

// ---------------------------------------------------------------------------
// Dtype detection: scan first 64K 16-bit words of trg. fp32 data -> ~128 words
// whose bf16-exponent bits are all-ones; bf16 N(0,1) data -> 0.
// ---------------------------------------------------------------------------
__global__ __launch_bounds__(256) void kdetect(const unsigned short* __restrict__ w,
                                               int* __restrict__ flag)
{
  __shared__ int cnt;
  if (threadIdx.x == 0) cnt = 0;
  __syncthreads();
  int c = 0;
  for (int i = threadIdx.x; i < 65536; i += 256)
    c += (((w[i] >> 7) & 0xFF) == 0xFF);
  atomicAdd(&cnt, c);
  __syncthreads();
  if (threadIdx.x == 0) *flag = (cnt > 16) ? 1 : 0;
}

__global__ __launch_bounds__(256) void kcvt(const void* __restrict__ src,
                                            bf16* __restrict__ dst, long n,
                                            const int* __restrict__ flag)
{
  long i = (long)blockIdx.x * 256 + threadIdx.x;
  if (i >= n) return;
  if (*flag) dst[i] = (bf16)((const float*)src)[i];
  else       dst[i] = ((const bf16*)src)[i];
}

__global__ __launch_bounds__(256) void kout(const bf16* __restrict__ src,
                                            void* __restrict__ dst, long n,
                                            const int* __restrict__ flag)
{
  long i = (long)blockIdx.x * 256 + threadIdx.x;
  if (i >= n) return;
  if (*flag) ((float*)dst)[i] = (float)src[i];
  else       ((bf16*)dst)[i]  = src[i];
}

// ---------------------------------------------------------------------------
// Batched transpose with fused dtype conversion.
// ---------------------------------------------------------------------------
__global__ __launch_bounds__(256) void ktranspose(
    const void* __restrict__ in, bf16* __restrict__ out,
    int R, int C, int ldin, long ebase, long ibs0, long ibs1, int nb1, long obs,
    const int* __restrict__ flag, int mode)
{
  __shared__ bf16 tile[32][33];
  bool f32in = mode && *flag;
  int z = blockIdx.z;
  long base = ebase + (long)(z / nb1) * ibs0 + (long)(z % nb1) * ibs1;
  bf16* dst = out + (long)z * obs;
  int r0 = blockIdx.x * 32, c0 = blockIdx.y * 32;
  int tx = threadIdx.x, ty = threadIdx.y;
  const float* fp = (const float*)in;
  const bf16*  bp = (const bf16*)in;
#pragma unroll
  for (int i = 0; i < 32; i += 8) {
    long idx = base + (long)(r0 + ty + i) * ldin + (c0 + tx);
    tile[ty + i][tx] = f32in ? (bf16)fp[idx] : bp[idx];
  }
  __syncthreads();
#pragma unroll
  for (int i = 0; i < 32; i += 8)
    dst[(long)(c0 + ty + i) * R + (r0 + tx)] = tile[tx][ty + i];
}

// ---------------------------------------------------------------------------
// Legacy batched NT GEMM (m97 structure) — kept for S=QK^T, PV, cross-Q.
// ---------------------------------------------------------------------------
template<int BM, int BN, int WM, int WN, bool RELU>
__global__ __launch_bounds__(256) void kgemm_nt(
    const bf16* __restrict__ A, const bf16* __restrict__ B, bf16* __restrict__ C,
    const bf16* __restrict__ bias, int K, int lda, int ldb, int ldc,
    long aB0, long aB1, long bB0, long bB1, long cB0, long cB1,
    int nb1, float scale)
{
  constexpr int TM = BM / WM, TN = BN / WN;
  constexpr int FM = TM / 16, FN = TN / 16;
  __shared__ __align__(16) bf16 At[BM * 64];
  __shared__ __align__(16) bf16 Bt[BN * 64];

  int z = blockIdx.z, z0 = z / nb1, z1 = z % nb1;
  const bf16* Ab = A + z0 * aB0 + z1 * aB1;
  const bf16* Bb = B + z0 * bB0 + z1 * bB1;
  bf16* Cb = C + z0 * cB0 + z1 * cB1;

  int row0 = blockIdx.x * BM, col0 = blockIdx.y * BN;
  int t = threadIdx.x;
  int lane = t & 63, w = t >> 6;
  int wm = w / WN, wn = w % WN;
  int m16 = lane & 15, quad = lane >> 4;

  f32x4 acc[FM][FN];
#pragma unroll
  for (int i = 0; i < FM; i++)
#pragma unroll
    for (int j = 0; j < FN; j++)
      acc[i][j] = f32x4{0.f, 0.f, 0.f, 0.f};

  int sr = t >> 3, sc = (t & 7) * 8;
  const bf16* ga = Ab + (long)(row0 + sr) * lda + sc;
  const bf16* gb = Bb + (long)(col0 + sr) * ldb + sc;

  for (int k0 = 0; k0 < K; k0 += 64) {
#pragma unroll
    for (int i = 0; i < BM / 32; i++)
      __builtin_amdgcn_global_load_lds(GAS(ga + (long)i * 32 * lda + k0),
                                       LAS(&At[t * 8 + i * 2048]), 16, 0, 0);
#pragma unroll
    for (int i = 0; i < BN / 32; i++)
      __builtin_amdgcn_global_load_lds(GAS(gb + (long)i * 32 * ldb + k0),
                                       LAS(&Bt[t * 8 + i * 2048]), 16, 0, 0);
    __syncthreads();
#pragma unroll
    for (int s = 0; s < 2; s++) {
      bf16x8 af[FM], bfr[FN];
#pragma unroll
      for (int i = 0; i < FM; i++)
        af[i] = *(const bf16x8*)&At[(wm * TM + i * 16 + m16) * 64 + s * 32 + quad * 8];
#pragma unroll
      for (int j = 0; j < FN; j++)
        bfr[j] = *(const bf16x8*)&Bt[(wn * TN + j * 16 + m16) * 64 + s * 32 + quad * 8];
#pragma unroll
      for (int i = 0; i < FM; i++)
#pragma unroll
        for (int j = 0; j < FN; j++)
          acc[i][j] = __builtin_amdgcn_mfma_f32_16x16x32_bf16(af[i], bfr[j], acc[i][j], 0, 0, 0);
    }
    __syncthreads();
  }

#pragma unroll
  for (int j = 0; j < FN; j++) {
    int col = col0 + wn * TN + j * 16 + m16;
    float bv = bias ? (float)bias[col] : 0.f;
#pragma unroll
    for (int i = 0; i < FM; i++) {
      int row = row0 + wm * TM + i * 16 + quad * 4;
#pragma unroll
      for (int r = 0; r < 4; r++) {
        float v = acc[i][j][r] * scale + bv;
        if (RELU) v = fmaxf(v, 0.f);
        Cb[(long)(row + r) * ldc + col] = (bf16)v;
      }
    }
  }
}

// ---------------------------------------------------------------------------
// 256x256 8-phase NT GEMM (m201-style T2+T3+T5 stack), 8 waves (2Mx4N),
// BK=64, 128KB double-buffered LDS with st-XOR swizzle.
//  - LDS layout: linear dest for global_load_lds; logical (r,c) stored at
//    byte r*128 + ((c*2) ^ ((r&7)<<4)). Inverse applied to the GLOBAL source
//    octet per staging thread (rule #21: linear dest + inv-swz source + swz read).
//  - Per K-tile: 4 phases {ds_read quadrant || (ph0: issue next-tile loads)
//    -> s_barrier -> lgkmcnt(0) -> setprio(1) + 16 MFMA -> (ph3: vmcnt(0))
//    -> s_barrier}. vmcnt drained once per K-tile, after ~3 phases of cover.
//  - blockIdx.z = K-split index (writes fp32 partials when F32OUT).
// ---------------------------------------------------------------------------
template<bool RELU, bool F32OUT>
__global__ __launch_bounds__(512, 2) void kgemm256(
    const bf16* __restrict__ A, const bf16* __restrict__ B, void* __restrict__ Cv,
    const bf16* __restrict__ bias, int K, int lda, int ldb, int ldc)
{
  __shared__ __align__(16) bf16 As[2][256 * 64];   // 32KB x2
  __shared__ __align__(16) bf16 Bs[2][256 * 64];   // 32KB x2  -> 128KB total

  const int t = threadIdx.x;
  const int lane = t & 63;
  const int w = t >> 6, wm = w >> 2, wn = w & 3;   // 2 x 4 waves
  const int m16 = lane & 15, quad = lane >> 4;

  const long zk = (long)blockIdx.z * K;            // K-split offset
  const int row0 = blockIdx.x * 256, col0 = blockIdx.y * 256;

  // staging: thread t writes LDS bytes [t*16, t*16+16) of each 8KB quarter;
  // the global source octet is XOR-permuted to realize the swizzle.
  const int sr = t >> 3;                           // 0..63 row within quarter
  const int so = (((t & 7) ^ (sr & 7)) << 3);      // source col (elements)
  const bf16* ga = A + zk + (long)(row0 + sr) * lda + so;
  const bf16* gb = B + zk + (long)(col0 + sr) * ldb + so;

  f32x4 acc[8][4];
#pragma unroll
  for (int i = 0; i < 8; i++)
#pragma unroll
    for (int j = 0; j < 4; j++) acc[i][j] = f32x4{0.f, 0.f, 0.f, 0.f};

  // swizzled read offsets (row&7 == m16&7 for all fragment rows)
  const int xo   = (m16 & 7) << 4;
  const int coA0 = (quad * 16) ^ xo;               // kstep s=0
  const int coA1 = (64 + quad * 16) ^ xo;          // kstep s=1

  const int NT = K / 64;

  auto stage = [&](int kt, int buf) {
    const bf16* _a = ga + kt * 64;
    const bf16* _b = gb + kt * 64;
    char* _la = (char*)&As[buf][0] + t * 16;
    char* _lb = (char*)&Bs[buf][0] + t * 16;
#pragma unroll
    for (int q = 0; q < 4; q++)
      __builtin_amdgcn_global_load_lds(GAS(_a + (long)q * 64 * lda),
                                       LAS(_la + q * 8192), 16, 0, 0);
#pragma unroll
    for (int q = 0; q < 4; q++)
      __builtin_amdgcn_global_load_lds(GAS(_b + (long)q * 64 * ldb),
                                       LAS(_lb + q * 8192), 16, 0, 0);
  };

  // prologue: tile 0 -> buf 0, drain, publish
  stage(0, 0);
  asm volatile("s_waitcnt vmcnt(0)" ::: "memory");
  __builtin_amdgcn_s_barrier();

  bf16x8 af[4][2];
  for (int kt = 0; kt < NT; kt++) {
    const int cur = kt & 1;
    const char* Ab = (const char*)&As[cur][0];
    const char* Bb = (const char*)&Bs[cur][0];
#pragma unroll
    for (int ph = 0; ph < 4; ph++) {
      const int qm = ph >> 1, qn = ph & 1;
      if (qn == 0) {                                  // A-half reused across qn pair
#pragma unroll
        for (int im = 0; im < 4; im++) {
          const int r = wm * 128 + (qm * 4 + im) * 16 + m16;
          af[im][0] = *(const bf16x8*)(Ab + r * 128 + coA0);
          af[im][1] = *(const bf16x8*)(Ab + r * 128 + coA1);
        }
      }
      bf16x8 bfr[2][2];
#pragma unroll
      for (int jn = 0; jn < 2; jn++) {
        const int r = wn * 64 + (qn * 2 + jn) * 16 + m16;
        bfr[jn][0] = *(const bf16x8*)(Bb + r * 128 + coA0);
        bfr[jn][1] = *(const bf16x8*)(Bb + r * 128 + coA1);
      }
      if (ph == 0 && kt + 1 < NT) stage(kt + 1, cur ^ 1);
      __builtin_amdgcn_s_barrier();
      asm volatile("s_waitcnt lgkmcnt(0)" ::: "memory");
      __builtin_amdgcn_sched_barrier(0);
      __builtin_amdgcn_s_setprio(1);
#pragma unroll
      for (int s = 0; s < 2; s++)
#pragma unroll
        for (int im = 0; im < 4; im++)
#pragma unroll
          for (int jn = 0; jn < 2; jn++)
            acc[qm * 4 + im][qn * 2 + jn] =
                __builtin_amdgcn_mfma_f32_16x16x32_bf16(
                    af[im][s], bfr[jn][s], acc[qm * 4 + im][qn * 2 + jn], 0, 0, 0);
      __builtin_amdgcn_s_setprio(0);
      if (ph == 3) asm volatile("s_waitcnt vmcnt(0)" ::: "memory");
      __builtin_amdgcn_s_barrier();
    }
  }

  // epilogue — C/D layout: col = lane&15, row = (lane>>4)*4 + reg
  if constexpr (F32OUT) {
    float* Cf = (float*)Cv + (long)blockIdx.z * gridDim.x * 256 * ldc;
#pragma unroll
    for (int j = 0; j < 4; j++) {
      const int col = col0 + wn * 64 + j * 16 + m16;
#pragma unroll
      for (int i = 0; i < 8; i++) {
        const int row = row0 + wm * 128 + i * 16 + quad * 4;
#pragma unroll
        for (int r = 0; r < 4; r++)
          Cf[(long)(row + r) * ldc + col] = acc[i][j][r];
      }
    }
  } else {
    bf16* Cb = (bf16*)Cv;
#pragma unroll
    for (int j = 0; j < 4; j++) {
      const int col = col0 + wn * 64 + j * 16 + m16;
      const float bv = (float)bias[col];
#pragma unroll
      for (int i = 0; i < 8; i++) {
        const int row = row0 + wm * 128 + i * 16 + quad * 4;
#pragma unroll
        for (int r = 0; r < 4; r++) {
          float v = acc[i][j][r] + bv;
          if (RELU) v = fmaxf(v, 0.f);
          Cb[(long)(row + r) * ldc + col] = (bf16)v;
        }
      }
    }
  }
}

// ---------------------------------------------------------------------------
// Row softmax over S[bh][q][0:512], optional mask (-10000 where mask==0).
// ---------------------------------------------------------------------------
__global__ __launch_bounds__(256) void ksoftmax(
    bf16* __restrict__ S, const int* __restrict__ mask)
{
  int q = blockIdx.x, bh = blockIdx.y, b = bh >> 4;
  bf16* row = S + ((long)bh * SEQLEN + q) * SEQLEN;
  int t = threadIdx.x;
  float v0 = (float)row[t], v1 = (float)row[t + 256];
  if (mask) {
    const int* mrow = mask + ((long)b * SEQLEN + q) * SEQLEN;
    if (mrow[t] == 0)       v0 = -10000.f;
    if (mrow[t + 256] == 0) v1 = -10000.f;
  }
  float mx = fmaxf(v0, v1);
#pragma unroll
  for (int off = 32; off > 0; off >>= 1) mx = fmaxf(mx, __shfl_down(mx, off));
  __shared__ float r1[4], r2[4];
  if ((t & 63) == 0) r1[t >> 6] = mx;
  __syncthreads();
  mx = fmaxf(fmaxf(r1[0], r1[1]), fmaxf(r1[2], r1[3]));
  float e0 = __expf(v0 - mx), e1 = __expf(v1 - mx);
  float s = e0 + e1;
#pragma unroll
  for (int off = 32; off > 0; off >>= 1) s += __shfl_down(s, off);
  if ((t & 63) == 0) r2[t >> 6] = s;
  __syncthreads();
  float inv = 1.f / (r2[0] + r2[1] + r2[2] + r2[3]);
  row[t]       = (bf16)(e0 * inv);
  row[t + 256] = (bf16)(e1 * inv);
}

// ---------------------------------------------------------------------------
// Fused residual add + LayerNorm: x = LN(h + x) * g + b (fp32 math).
// ---------------------------------------------------------------------------
__global__ __launch_bounds__(256) void kaddln(
    const bf16* __restrict__ h, bf16* __restrict__ x,
    const bf16* __restrict__ g, const bf16* __restrict__ b)
{
  long row = blockIdx.x;
  const bf16* hr = h + row * DMODEL;
  bf16* xr = x + row * DMODEL;
  int t = threadIdx.x;
  bf16x4 hv = *(const bf16x4*)&hr[t * 4];
  bf16x4 xv = *(const bf16x4*)&xr[t * 4];
  float v[4]; float s1 = 0.f, s2 = 0.f;
#pragma unroll
  for (int i = 0; i < 4; i++) {
    v[i] = (float)hv[i] + (float)xv[i];
    s1 += v[i]; s2 += v[i] * v[i];
  }
#pragma unroll
  for (int off = 32; off > 0; off >>= 1) {
    s1 += __shfl_down(s1, off);
    s2 += __shfl_down(s2, off);
  }
  __shared__ float a1[4], a2[4];
  if ((t & 63) == 0) { a1[t >> 6] = s1; a2[t >> 6] = s2; }
  __syncthreads();
  s1 = a1[0] + a1[1] + a1[2] + a1[3];
  s2 = a2[0] + a2[1] + a2[2] + a2[3];
  float mean = s1 * (1.f / DMODEL);
  float var  = s2 * (1.f / DMODEL) - mean * mean;
  float rstd = rsqrtf(var + 1e-12f);
  bf16x4 gv = *(const bf16x4*)&g[t * 4];
  bf16x4 bv = *(const bf16x4*)&b[t * 4];
  bf16x4 o;
#pragma unroll
  for (int i = 0; i < 4; i++)
    o[i] = (bf16)(((v[i] - mean) * rstd) * (float)gv[i] + (float)bv[i]);
  *(bf16x4*)&xr[t * 4] = o;
}

// ---------------------------------------------------------------------------
// Split-K reduce + bias + residual add + LayerNorm:
// x = LN(h0 + h1 + bias + x) * g + b  (h0,h1 fp32 partials from kgemm256).
// ---------------------------------------------------------------------------
__global__ __launch_bounds__(256) void kaddln2(
    const float* __restrict__ h0, const float* __restrict__ h1,
    const bf16* __restrict__ bias, bf16* __restrict__ x,
    const bf16* __restrict__ g, const bf16* __restrict__ b)
{
  long row = blockIdx.x;
  const float* h0r = h0 + row * DMODEL;
  const float* h1r = h1 + row * DMODEL;
  bf16* xr = x + row * DMODEL;
  int t = threadIdx.x;
  f32x4 a0 = *(const f32x4*)&h0r[t * 4];
  f32x4 a1 = *(const f32x4*)&h1r[t * 4];
  bf16x4 xv = *(const bf16x4*)&xr[t * 4];
  bf16x4 bi = *(const bf16x4*)&bias[t * 4];
  float v[4]; float s1 = 0.f, s2 = 0.f;
#pragma unroll
  for (int i = 0; i < 4; i++) {
    v[i] = a0[i] + a1[i] + (float)bi[i] + (float)xv[i];
    s1 += v[i]; s2 += v[i] * v[i];
  }
#pragma unroll
  for (int off = 32; off > 0; off >>= 1) {
    s1 += __shfl_down(s1, off);
    s2 += __shfl_down(s2, off);
  }
  __shared__ float r1[4], r2[4];
  if ((t & 63) == 0) { r1[t >> 6] = s1; r2[t >> 6] = s2; }
  __syncthreads();
  s1 = r1[0] + r1[1] + r1[2] + r1[3];
  s2 = r2[0] + r2[1] + r2[2] + r2[3];
  float mean = s1 * (1.f / DMODEL);
  float var  = s2 * (1.f / DMODEL) - mean * mean;
  float rstd = rsqrtf(var + 1e-12f);
  bf16x4 gv = *(const bf16x4*)&g[t * 4];
  bf16x4 bv = *(const bf16x4*)&b[t * 4];
  bf16x4 o;
#pragma unroll
  for (int i = 0; i < 4; i++)
    o[i] = (bf16)(((v[i] - mean) * rstd) * (float)gv[i] + (float)bv[i]);
  *(bf16x4*)&xr[t * 4] = o;
}

// ---------------------------------------------------------------------------
extern "C" void kernel_launch(void* const* d_in, const int* in_sizes, int n_in,
                              void* d_out, int out_size, void* d_ws, size_t ws_size,
                              hipStream_t stream)
{
  (void)in_sizes; (void)n_in; (void)out_size; (void)ws_size;
  const void* trg_r  = d_in[0];
  const void* enc_r  = d_in[1];
  const int*  mask   = (const int*)d_in[2];
  const void* sa_w_r = d_in[3];
  const void* sa_b_r = d_in[4];
  const void* ca_w_r = d_in[5];
  const void* ca_b_r = d_in[6];
  const void* ln_g_r = d_in[7];
  const void* ln_b_r = d_in[8];
  const void* w1_r   = d_in[9];
  const void* b1_r   = d_in[10];
  const void* w2_r   = d_in[11];
  const void* b2_r   = d_in[12];

  const size_t XD = (size_t)MTOK * DMODEL;        // 4,194,304 elements
  char* p = (char*)d_ws;
  int*  flag = (int*)p;       p += 256;
  bf16* pSaB = (bf16*)p;      p += (size_t)NLAYER * 4 * DMODEL * 2;
  bf16* pCaB = (bf16*)p;      p += (size_t)NLAYER * 4 * DMODEL * 2;
  bf16* pLnG = (bf16*)p;      p += (size_t)NLAYER * 3 * DMODEL * 2;
  bf16* pLnB = (bf16*)p;      p += (size_t)NLAYER * 3 * DMODEL * 2;
  bf16* pB1  = (bf16*)p;      p += (size_t)NLAYER * FFDIM * 2;
  bf16* pB2  = (bf16*)p;      p += (size_t)NLAYER * DMODEL * 2;
  p = (char*)d_ws + (1 << 20);                                             // 1MB mark
  bf16* x    = (bf16*)p; p += XD * 2;                                      // 8MB
  bf16* encB = (bf16*)p; p += XD * 2;                                      // 8MB
  bf16* qkv  = (bf16*)p; p += (size_t)MTOK * QKVLD * 2;                    // 24MB
  bf16* ob   = (bf16*)p; p += XD * 2;                                      // 8MB
  bf16* hb   = (bf16*)p; p += XD * 2;                                      // 8MB (unused now)
  bf16* Vt   = (bf16*)p; p += (size_t)BATCH * NHEAD * DHEAD * SEQLEN * 2;  // 8MB
  bf16* Wt   = (bf16*)p; p += (size_t)4 * DMODEL * DMODEL * 2;             // 8MB
  bf16* big  = (bf16*)p; p += (size_t)BATCH * NHEAD * SEQLEN * SEQLEN * 2; // 64MB
  bf16* Sb   = big;
  bf16* ffh  = big;
  (void)hb;
  // fp32 split-K partial buffers (time-share `big`):
  //  - out-proj partials: big[0 .. 32MB)  (Sb dead after PV)
  //  - FFN-down partials: big[32MB .. 64MB)  (ffh occupies [0,32MB))
  float* Pf  = (float*)big;
  float* PfF = (float*)((char*)big + 33554432);
  const long PZ = (long)MTOK * DMODEL;     // elements per fp32 partial

  const long PQ = (long)SEQLEN * QKVLD;    // 1572864: batch stride in qkv buffer
  const long PD = (long)SEQLEN * DMODEL;   // 524288
  const long SS = (long)SEQLEN * SEQLEN;   // 262144
  const long VS = (long)DHEAD * SEQLEN;    // 32768
  const long DD = (long)DMODEL * DMODEL;   // 1048576

  // --- dtype detection + input conversion ---
  kdetect<<<1, 256, 0, stream>>>((const unsigned short*)trg_r, flag);
  int nb = (int)((XD + 255) / 256);
  kcvt<<<nb, 256, 0, stream>>>(trg_r, x,    (long)XD, flag);
  kcvt<<<nb, 256, 0, stream>>>(enc_r, encB, (long)XD, flag);
  kcvt<<<96,  256, 0, stream>>>(sa_b_r, pSaB, (long)NLAYER * 4 * DMODEL, flag);
  kcvt<<<96,  256, 0, stream>>>(ca_b_r, pCaB, (long)NLAYER * 4 * DMODEL, flag);
  kcvt<<<72,  256, 0, stream>>>(ln_g_r, pLnG, (long)NLAYER * 3 * DMODEL, flag);
  kcvt<<<72,  256, 0, stream>>>(ln_b_r, pLnB, (long)NLAYER * 3 * DMODEL, flag);
  kcvt<<<96,  256, 0, stream>>>(b1_r,   pB1,  (long)NLAYER * FFDIM,      flag);
  kcvt<<<24,  256, 0, stream>>>(b2_r,   pB2,  (long)NLAYER * DMODEL,     flag);

  dim3 tb(32, 8, 1);
  for (int l = 0; l < NLAYER; l++) {
    for (int att = 0; att < 2; att++) {
      const void* Wraw = (att == 0) ? sa_w_r : ca_w_r;
      const bf16* Bv   = ((att == 0) ? pSaB : pCaB) + (size_t)l * 4 * DMODEL;
      const int*  mk   = (att == 0) ? mask : nullptr;

      // transpose (+convert) 4 weights [K][N] -> Wt[i][N][K]; q|k|v contiguous
      ktranspose<<<dim3(32, 32, 4), tb, 0, stream>>>(
          Wraw, Wt, DMODEL, DMODEL, DMODEL, (long)l * 4 * DD, 0, DD, 4, DD, flag, 1);
      if (att == 0) {
        // fused QKV: [4096,1024] @ [3072,1024]^T -> qkv[4096,3072]  (192 blocks)
        kgemm256<false, false><<<dim3(16, 12, 1), 512, 0, stream>>>(
            x, Wt, qkv, Bv, 1024, 1024, 1024, QKVLD);
      } else {
        // Q from x (legacy 64x128, 512 blocks); K|V fused from enc (128 blocks)
        kgemm_nt<64,128,2,2,false><<<dim3(64, 8, 1), 256, 0, stream>>>(
            x, Wt, qkv, Bv, 1024, 1024, 1024, QKVLD, 0,0,0,0,0,0, 1, 1.f);
        kgemm256<false, false><<<dim3(16, 8, 1), 512, 0, stream>>>(
            encB, Wt + DD, qkv + 1024, Bv + 1024, 1024, 1024, 1024, QKVLD);
      }
      // S[bh] = (Q_bh @ K_bh^T) / 8  over 128 (b,h) pairs (2048 blocks)
      kgemm_nt<128,128,2,2,false><<<dim3(4, 4, 128), 256, 0, stream>>>(
          qkv, qkv + 1024, Sb, nullptr, 64, QKVLD, QKVLD, 512,
          PQ, 64, PQ, 64, 16 * SS, SS, 16, 0.125f);
      ksoftmax<<<dim3(512, 128), 256, 0, stream>>>(Sb, mk);
      // Vt[bh][d][j] = V[bh][j][d]
      ktranspose<<<dim3(16, 2, 128), tb, 0, stream>>>(
          qkv + 2048, Vt, SEQLEN, DHEAD, QKVLD, 0, PQ, 64, 16, VS, flag, 0);
      // O[bh] = P_bh @ V_bh (512 blocks)
      kgemm_nt<128,64,2,2,false><<<dim3(4, 1, 128), 256, 0, stream>>>(
          Sb, Vt, ob, nullptr, 512, 512, 512, 1024,
          16 * SS, SS, 16 * VS, VS, PD, 64, 16, 1.f);
      // output projection: split-K=2, fp32 partials into Pf (Sb is dead now)
      kgemm256<false, true><<<dim3(16, 4, 2), 512, 0, stream>>>(
          ob, Wt + 3 * DD, Pf, nullptr, 512, 1024, 1024, 1024);
      // x = LN(P0 + P1 + biasO + x)
      kaddln2<<<dim3(MTOK), 256, 0, stream>>>(Pf, Pf + PZ, Bv + 3 * DMODEL, x,
          pLnG + (size_t)(l * 3 + att) * DMODEL, pLnB + (size_t)(l * 3 + att) * DMODEL);
    }

    // ===================== FFN =====================
    ktranspose<<<dim3(32, 128, 1), tb, 0, stream>>>(
        w1_r, Wt, DMODEL, FFDIM, FFDIM, (long)l * DMODEL * FFDIM, 0, 0, 1, 0, flag, 1);
    // FFN up: 4096x4096x1024, ReLU (256 blocks)
    kgemm256<true, false><<<dim3(16, 16, 1), 512, 0, stream>>>(
        x, Wt, ffh, pB1 + (size_t)l * FFDIM, 1024, 1024, 1024, 4096);
    ktranspose<<<dim3(128, 32, 1), tb, 0, stream>>>(
        w2_r, Wt, FFDIM, DMODEL, DMODEL, (long)l * FFDIM * DMODEL, 0, 0, 1, 0, flag, 1);
    // FFN down: split-K=2 (K=2048 each), fp32 partials into upper half of big
    kgemm256<false, true><<<dim3(16, 4, 2), 512, 0, stream>>>(
        ffh, Wt, PfF, nullptr, 2048, 4096, 4096, 1024);
    kaddln2<<<dim3(MTOK), 256, 0, stream>>>(PfF, PfF + PZ, pB2 + (size_t)l * DMODEL, x,
        pLnG + (size_t)(l * 3 + 2) * DMODEL, pLnB + (size_t)(l * 3 + 2) * DMODEL);
  }

  kout<<<nb, 256, 0, stream>>>(x, d_out, (long)XD, flag);
}

// Round 3
// 3351.579 us; speedup vs baseline: 1.0456x; 1.0450x over previous
//
#include <hip/hip_runtime.h>

typedef __bf16 bf16;
typedef __bf16 bf16x8 __attribute__((ext_vector_type(8)));
typedef __bf16 bf16x4 __attribute__((ext_vector_type(4)));
typedef float  f32x4  __attribute__((ext_vector_type(4)));

#define NLAYER 6
#define DMODEL 1024
#define NHEAD  16
#define DHEAD  64
#define FFDIM  4096
#define BATCH  8
#define SEQLEN 512
#define MTOK   (BATCH * SEQLEN)   // 4096 tokens
#define QKVLD  3072               // fused q|k|v row stride

#define GAS(p) ((const __attribute__((address_space(1))) void*)(p))
#define LAS(p) ((__attribute__((address_space(3))) void*)(p))

// ---------------------------------------------------------------------------
// Dtype detection: scan first 64K 16-bit words of trg. fp32 data -> ~128 words
// whose bf16-exponent bits are all-ones; bf16 N(0,1) data -> 0.
// ---------------------------------------------------------------------------
__global__ __launch_bounds__(256) void kdetect(const unsigned short* __restrict__ w,
                                               int* __restrict__ flag)
{
  __shared__ int cnt;
  if (threadIdx.x == 0) cnt = 0;
  __syncthreads();
  int c = 0;
  for (int i = threadIdx.x; i < 65536; i += 256)
    c += (((w[i] >> 7) & 0xFF) == 0xFF);
  atomicAdd(&cnt, c);
  __syncthreads();
  if (threadIdx.x == 0) *flag = (cnt > 16) ? 1 : 0;
}

__global__ __launch_bounds__(256) void kcvt(const void* __restrict__ src,
                                            bf16* __restrict__ dst, long n,
                                            const int* __restrict__ flag)
{
  long i = (long)blockIdx.x * 256 + threadIdx.x;
  if (i >= n) return;
  if (*flag) dst[i] = (bf16)((const float*)src)[i];
  else       dst[i] = ((const bf16*)src)[i];
}

__global__ __launch_bounds__(256) void kout(const bf16* __restrict__ src,
                                            void* __restrict__ dst, long n,
                                            const int* __restrict__ flag)
{
  long i = (long)blockIdx.x * 256 + threadIdx.x;
  if (i >= n) return;
  if (*flag) ((float*)dst)[i] = (float)src[i];
  else       ((bf16*)dst)[i]  = src[i];
}

// ---------------------------------------------------------------------------
// Batched transpose with fused dtype conversion.
// ---------------------------------------------------------------------------
__global__ __launch_bounds__(256) void ktranspose(
    const void* __restrict__ in, bf16* __restrict__ out,
    int R, int C, int ldin, long ebase, long ibs0, long ibs1, int nb1, long obs,
    const int* __restrict__ flag, int mode)
{
  __shared__ bf16 tile[32][33];
  bool f32in = mode && *flag;
  int z = blockIdx.z;
  long base = ebase + (long)(z / nb1) * ibs0 + (long)(z % nb1) * ibs1;
  bf16* dst = out + (long)z * obs;
  int r0 = blockIdx.x * 32, c0 = blockIdx.y * 32;
  int tx = threadIdx.x, ty = threadIdx.y;
  const float* fp = (const float*)in;
  const bf16*  bp = (const bf16*)in;
#pragma unroll
  for (int i = 0; i < 32; i += 8) {
    long idx = base + (long)(r0 + ty + i) * ldin + (c0 + tx);
    tile[ty + i][tx] = f32in ? (bf16)fp[idx] : bp[idx];
  }
  __syncthreads();
#pragma unroll
  for (int i = 0; i < 32; i += 8)
    dst[(long)(c0 + ty + i) * R + (r0 + tx)] = tile[tx][ty + i];
}

// ---------------------------------------------------------------------------
// Legacy batched NT GEMM (m97 structure) — kept for S=QK^T, PV, cross-Q.
// ---------------------------------------------------------------------------
template<int BM, int BN, int WM, int WN, bool RELU>
__global__ __launch_bounds__(256) void kgemm_nt(
    const bf16* __restrict__ A, const bf16* __restrict__ B, bf16* __restrict__ C,
    const bf16* __restrict__ bias, int K, int lda, int ldb, int ldc,
    long aB0, long aB1, long bB0, long bB1, long cB0, long cB1,
    int nb1, float scale)
{
  constexpr int TM = BM / WM, TN = BN / WN;
  constexpr int FM = TM / 16, FN = TN / 16;
  __shared__ __align__(16) bf16 At[BM * 64];
  __shared__ __align__(16) bf16 Bt[BN * 64];

  int z = blockIdx.z, z0 = z / nb1, z1 = z % nb1;
  const bf16* Ab = A + z0 * aB0 + z1 * aB1;
  const bf16* Bb = B + z0 * bB0 + z1 * bB1;
  bf16* Cb = C + z0 * cB0 + z1 * cB1;

  int row0 = blockIdx.x * BM, col0 = blockIdx.y * BN;
  int t = threadIdx.x;
  int lane = t & 63, w = t >> 6;
  int wm = w / WN, wn = w % WN;
  int m16 = lane & 15, quad = lane >> 4;

  f32x4 acc[FM][FN];
#pragma unroll
  for (int i = 0; i < FM; i++)
#pragma unroll
    for (int j = 0; j < FN; j++)
      acc[i][j] = f32x4{0.f, 0.f, 0.f, 0.f};

  int sr = t >> 3, sc = (t & 7) * 8;
  const bf16* ga = Ab + (long)(row0 + sr) * lda + sc;
  const bf16* gb = Bb + (long)(col0 + sr) * ldb + sc;

  for (int k0 = 0; k0 < K; k0 += 64) {
#pragma unroll
    for (int i = 0; i < BM / 32; i++)
      __builtin_amdgcn_global_load_lds(GAS(ga + (long)i * 32 * lda + k0),
                                       LAS(&At[t * 8 + i * 2048]), 16, 0, 0);
#pragma unroll
    for (int i = 0; i < BN / 32; i++)
      __builtin_amdgcn_global_load_lds(GAS(gb + (long)i * 32 * ldb + k0),
                                       LAS(&Bt[t * 8 + i * 2048]), 16, 0, 0);
    __syncthreads();
#pragma unroll
    for (int s = 0; s < 2; s++) {
      bf16x8 af[FM], bfr[FN];
#pragma unroll
      for (int i = 0; i < FM; i++)
        af[i] = *(const bf16x8*)&At[(wm * TM + i * 16 + m16) * 64 + s * 32 + quad * 8];
#pragma unroll
      for (int j = 0; j < FN; j++)
        bfr[j] = *(const bf16x8*)&Bt[(wn * TN + j * 16 + m16) * 64 + s * 32 + quad * 8];
#pragma unroll
      for (int i = 0; i < FM; i++)
#pragma unroll
        for (int j = 0; j < FN; j++)
          acc[i][j] = __builtin_amdgcn_mfma_f32_16x16x32_bf16(af[i], bfr[j], acc[i][j], 0, 0, 0);
    }
    __syncthreads();
  }

#pragma unroll
  for (int j = 0; j < FN; j++) {
    int col = col0 + wn * TN + j * 16 + m16;
    float bv = bias ? (float)bias[col] : 0.f;
#pragma unroll
    for (int i = 0; i < FM; i++) {
      int row = row0 + wm * TM + i * 16 + quad * 4;
#pragma unroll
      for (int r = 0; r < 4; r++) {
        float v = acc[i][j][r] * scale + bv;
        if (RELU) v = fmaxf(v, 0.f);
        Cb[(long)(row + r) * ldc + col] = (bf16)v;
      }
    }
  }
}

// ---------------------------------------------------------------------------
// 256x256 NT GEMM, 8 waves (2Mx4N), BK=64, 128KB double-buffered swizzled LDS.
// Counted-vmcnt schedule (T3+T4, m218):
//  - 4 phases per K-tile; phase = (k-step s = ph>>1, row-quadrant qm = ph&1).
//  - B fragments (all 4 jn at step s) are read at qm==0 and REUSED at qm==1.
//  - Staging of tile t+1 is spread 2 quarter-loads per phase:
//      ph0: B-q0,B-q1   ph1: B-q2,B-q3   ph2: A-q0,A-q2   ph3: A-q1,A-q3
//    (consumption priority: next tile's ph0 needs all B + A-q0/q2; A-q1/q3
//     are only needed at next tile's ph1.)
//  - Gates: s_waitcnt vmcnt(2) before the phase-ending barrier at ph0 and ph3
//    (per-wave wait + barrier => collective guarantee). Never vmcnt(0) in the
//    main loop; last tile uses vmcnt(0) at ph0 (nothing staged during it).
//  - LDS swizzle: logical (r,c) at byte r*128 + ((c*2) ^ ((r&7)<<4)); linear
//    global_load_lds dest + inverse-swizzled global source (rule #21).
// ---------------------------------------------------------------------------
template<bool RELU, bool F32OUT>
__global__ __launch_bounds__(512, 2) void kgemm256(
    const bf16* __restrict__ A, const bf16* __restrict__ B, void* __restrict__ Cv,
    const bf16* __restrict__ bias, int K, int lda, int ldb, int ldc)
{
  __shared__ __align__(16) bf16 As[2][256 * 64];   // 32KB x2
  __shared__ __align__(16) bf16 Bs[2][256 * 64];   // 32KB x2  -> 128KB total

  const int t = threadIdx.x;
  const int lane = t & 63;
  const int w = t >> 6, wm = w >> 2, wn = w & 3;   // 2 x 4 waves
  const int m16 = lane & 15, quad = lane >> 4;

  const long zk = (long)blockIdx.z * K;            // K-split offset
  const int row0 = blockIdx.x * 256, col0 = blockIdx.y * 256;

  // staging: thread t covers row sr = t>>3 (of a 64-row quarter), octet t&7;
  // global source octet XOR-permuted to realize the read-side swizzle.
  const int sr = t >> 3;
  const int so = (((t & 7) ^ (sr & 7)) << 3);
  const bf16* ga = A + zk + (long)(row0 + sr) * lda + so;
  const bf16* gb = B + zk + (long)(col0 + sr) * ldb + so;

  f32x4 acc[8][4];
#pragma unroll
  for (int i = 0; i < 8; i++)
#pragma unroll
    for (int j = 0; j < 4; j++) acc[i][j] = f32x4{0.f, 0.f, 0.f, 0.f};

  const int NT = K / 64;

  // one quarter = 64 rows x 64 cols = 8KB = 1 global_load_lds per thread
  auto stageA = [&](int tt, int q) {
    __builtin_amdgcn_global_load_lds(GAS(ga + (long)tt * 64 + (long)q * 64 * lda),
                                     LAS((char*)&As[tt & 1][0] + t * 16 + q * 8192),
                                     16, 0, 0);
  };
  auto stageB = [&](int tt, int q) {
    __builtin_amdgcn_global_load_lds(GAS(gb + (long)tt * 64 + (long)q * 64 * ldb),
                                     LAS((char*)&Bs[tt & 1][0] + t * 16 + q * 8192),
                                     16, 0, 0);
  };

  // prologue: tile 0 in consumption-priority order, counted gate (not drain)
  stageB(0, 0); stageB(0, 1); stageB(0, 2); stageB(0, 3);
  stageA(0, 0); stageA(0, 2); stageA(0, 1); stageA(0, 3);
  asm volatile("s_waitcnt vmcnt(2)" ::: "memory");   // A-q1/q3 may still fly
  __builtin_amdgcn_s_barrier();

  bf16x8 bfr[4];   // B frags for current k-step, reused across the qm pair
  for (int kt = 0; kt < NT; kt++) {
    const int cur = kt & 1;
    const char* Ab = (const char*)&As[cur][0];
    const char* Bb = (const char*)&Bs[cur][0];
    const bool more = (kt + 1 < NT);
#pragma unroll
    for (int ph = 0; ph < 4; ph++) {
      const int s  = ph >> 1;     // k-step within the 64-wide tile
      const int qm = ph & 1;      // row quadrant within this wave's 128 rows
      if (qm == 0) {
#pragma unroll
        for (int j = 0; j < 4; j++) {
          const int r = wn * 64 + j * 16 + m16;
          bfr[j] = *(const bf16x8*)(Bb + r * 128 + ((s * 64 + quad * 16) ^ ((r & 7) << 4)));
        }
      }
      bf16x8 af[4];
#pragma unroll
      for (int i = 0; i < 4; i++) {
        const int r = wm * 128 + (qm * 4 + i) * 16 + m16;
        af[i] = *(const bf16x8*)(Ab + r * 128 + ((s * 64 + quad * 16) ^ ((r & 7) << 4)));
      }
      if (more) {
        if      (ph == 0) { stageB(kt + 1, 0); stageB(kt + 1, 1); }
        else if (ph == 1) { stageB(kt + 1, 2); stageB(kt + 1, 3); }
        else if (ph == 2) { stageA(kt + 1, 0); stageA(kt + 1, 2); }
        else              { stageA(kt + 1, 1); stageA(kt + 1, 3); }
      }
      __builtin_amdgcn_s_barrier();
      asm volatile("s_waitcnt lgkmcnt(0)" ::: "memory");
      __builtin_amdgcn_sched_barrier(0);
      __builtin_amdgcn_s_setprio(1);
#pragma unroll
      for (int i = 0; i < 4; i++)
#pragma unroll
        for (int j = 0; j < 4; j++)
          acc[qm * 4 + i][j] = __builtin_amdgcn_mfma_f32_16x16x32_bf16(
              af[i], bfr[j], acc[qm * 4 + i][j], 0, 0, 0);
      __builtin_amdgcn_s_setprio(0);
      // counted gates: end-ph0 covers current tile's A-q1/q3; end-ph3 covers
      // everything the next tile's ph0 reads (B all + A-q0/q2).
      if (more) {
        if (ph == 0 || ph == 3) asm volatile("s_waitcnt vmcnt(2)" ::: "memory");
      } else {
        if (ph == 0) asm volatile("s_waitcnt vmcnt(0)" ::: "memory");
      }
      __builtin_amdgcn_s_barrier();
    }
  }

  // epilogue — C/D layout: col = lane&15, row = (lane>>4)*4 + reg
  if constexpr (F32OUT) {
    float* Cf = (float*)Cv + (long)blockIdx.z * gridDim.x * 256 * ldc;
#pragma unroll
    for (int j = 0; j < 4; j++) {
      const int col = col0 + wn * 64 + j * 16 + m16;
#pragma unroll
      for (int i = 0; i < 8; i++) {
        const int row = row0 + wm * 128 + i * 16 + quad * 4;
#pragma unroll
        for (int r = 0; r < 4; r++)
          Cf[(long)(row + r) * ldc + col] = acc[i][j][r];
      }
    }
  } else {
    bf16* Cb = (bf16*)Cv;
#pragma unroll
    for (int j = 0; j < 4; j++) {
      const int col = col0 + wn * 64 + j * 16 + m16;
      const float bv = (float)bias[col];
#pragma unroll
      for (int i = 0; i < 8; i++) {
        const int row = row0 + wm * 128 + i * 16 + quad * 4;
#pragma unroll
        for (int r = 0; r < 4; r++) {
          float v = acc[i][j][r] + bv;
          if (RELU) v = fmaxf(v, 0.f);
          Cb[(long)(row + r) * ldc + col] = (bf16)v;
        }
      }
    }
  }
}

// ---------------------------------------------------------------------------
// Row softmax over S[bh][q][0:512], optional mask (-10000 where mask==0).
// ---------------------------------------------------------------------------
__global__ __launch_bounds__(256) void ksoftmax(
    bf16* __restrict__ S, const int* __restrict__ mask)
{
  int q = blockIdx.x, bh = blockIdx.y, b = bh >> 4;
  bf16* row = S + ((long)bh * SEQLEN + q) * SEQLEN;
  int t = threadIdx.x;
  float v0 = (float)row[t], v1 = (float)row[t + 256];
  if (mask) {
    const int* mrow = mask + ((long)b * SEQLEN + q) * SEQLEN;
    if (mrow[t] == 0)       v0 = -10000.f;
    if (mrow[t + 256] == 0) v1 = -10000.f;
  }
  float mx = fmaxf(v0, v1);
#pragma unroll
  for (int off = 32; off > 0; off >>= 1) mx = fmaxf(mx, __shfl_down(mx, off));
  __shared__ float r1[4], r2[4];
  if ((t & 63) == 0) r1[t >> 6] = mx;
  __syncthreads();
  mx = fmaxf(fmaxf(r1[0], r1[1]), fmaxf(r1[2], r1[3]));
  float e0 = __expf(v0 - mx), e1 = __expf(v1 - mx);
  float s = e0 + e1;
#pragma unroll
  for (int off = 32; off > 0; off >>= 1) s += __shfl_down(s, off);
  if ((t & 63) == 0) r2[t >> 6] = s;
  __syncthreads();
  float inv = 1.f / (r2[0] + r2[1] + r2[2] + r2[3]);
  row[t]       = (bf16)(e0 * inv);
  row[t + 256] = (bf16)(e1 * inv);
}

// ---------------------------------------------------------------------------
// Fused residual add + LayerNorm: x = LN(h + x) * g + b (fp32 math).
// ---------------------------------------------------------------------------
__global__ __launch_bounds__(256) void kaddln(
    const bf16* __restrict__ h, bf16* __restrict__ x,
    const bf16* __restrict__ g, const bf16* __restrict__ b)
{
  long row = blockIdx.x;
  const bf16* hr = h + row * DMODEL;
  bf16* xr = x + row * DMODEL;
  int t = threadIdx.x;
  bf16x4 hv = *(const bf16x4*)&hr[t * 4];
  bf16x4 xv = *(const bf16x4*)&xr[t * 4];
  float v[4]; float s1 = 0.f, s2 = 0.f;
#pragma unroll
  for (int i = 0; i < 4; i++) {
    v[i] = (float)hv[i] + (float)xv[i];
    s1 += v[i]; s2 += v[i] * v[i];
  }
#pragma unroll
  for (int off = 32; off > 0; off >>= 1) {
    s1 += __shfl_down(s1, off);
    s2 += __shfl_down(s2, off);
  }
  __shared__ float a1[4], a2[4];
  if ((t & 63) == 0) { a1[t >> 6] = s1; a2[t >> 6] = s2; }
  __syncthreads();
  s1 = a1[0] + a1[1] + a1[2] + a1[3];
  s2 = a2[0] + a2[1] + a2[2] + a2[3];
  float mean = s1 * (1.f / DMODEL);
  float var  = s2 * (1.f / DMODEL) - mean * mean;
  float rstd = rsqrtf(var + 1e-12f);
  bf16x4 gv = *(const bf16x4*)&g[t * 4];
  bf16x4 bv = *(const bf16x4*)&b[t * 4];
  bf16x4 o;
#pragma unroll
  for (int i = 0; i < 4; i++)
    o[i] = (bf16)(((v[i] - mean) * rstd) * (float)gv[i] + (float)bv[i]);
  *(bf16x4*)&xr[t * 4] = o;
}

// ---------------------------------------------------------------------------
// Split-K reduce + bias + residual add + LayerNorm:
// x = LN(h0 + h1 + bias + x) * g + b  (h0,h1 fp32 partials from kgemm256).
// ---------------------------------------------------------------------------
__global__ __launch_bounds__(256) void kaddln2(
    const float* __restrict__ h0, const float* __restrict__ h1,
    const bf16* __restrict__ bias, bf16* __restrict__ x,
    const bf16* __restrict__ g, const bf16* __restrict__ b)
{
  long row = blockIdx.x;
  const float* h0r = h0 + row * DMODEL;
  const float* h1r = h1 + row * DMODEL;
  bf16* xr = x + row * DMODEL;
  int t = threadIdx.x;
  f32x4 a0 = *(const f32x4*)&h0r[t * 4];
  f32x4 a1 = *(const f32x4*)&h1r[t * 4];
  bf16x4 xv = *(const bf16x4*)&xr[t * 4];
  bf16x4 bi = *(const bf16x4*)&bias[t * 4];
  float v[4]; float s1 = 0.f, s2 = 0.f;
#pragma unroll
  for (int i = 0; i < 4; i++) {
    v[i] = a0[i] + a1[i] + (float)bi[i] + (float)xv[i];
    s1 += v[i]; s2 += v[i] * v[i];
  }
#pragma unroll
  for (int off = 32; off > 0; off >>= 1) {
    s1 += __shfl_down(s1, off);
    s2 += __shfl_down(s2, off);
  }
  __shared__ float r1[4], r2[4];
  if ((t & 63) == 0) { r1[t >> 6] = s1; r2[t >> 6] = s2; }
  __syncthreads();
  s1 = r1[0] + r1[1] + r1[2] + r1[3];
  s2 = r2[0] + r2[1] + r2[2] + r2[3];
  float mean = s1 * (1.f / DMODEL);
  float var  = s2 * (1.f / DMODEL) - mean * mean;
  float rstd = rsqrtf(var + 1e-12f);
  bf16x4 gv = *(const bf16x4*)&g[t * 4];
  bf16x4 bv = *(const bf16x4*)&b[t * 4];
  bf16x4 o;
#pragma unroll
  for (int i = 0; i < 4; i++)
    o[i] = (bf16)(((v[i] - mean) * rstd) * (float)gv[i] + (float)bv[i]);
  *(bf16x4*)&xr[t * 4] = o;
}

// ---------------------------------------------------------------------------
extern "C" void kernel_launch(void* const* d_in, const int* in_sizes, int n_in,
                              void* d_out, int out_size, void* d_ws, size_t ws_size,
                              hipStream_t stream)
{
  (void)in_sizes; (void)n_in; (void)out_size; (void)ws_size;
  const void* trg_r  = d_in[0];
  const void* enc_r  = d_in[1];
  const int*  mask   = (const int*)d_in[2];
  const void* sa_w_r = d_in[3];
  const void* sa_b_r = d_in[4];
  const void* ca_w_r = d_in[5];
  const void* ca_b_r = d_in[6];
  const void* ln_g_r = d_in[7];
  const void* ln_b_r = d_in[8];
  const void* w1_r   = d_in[9];
  const void* b1_r   = d_in[10];
  const void* w2_r   = d_in[11];
  const void* b2_r   = d_in[12];

  const size_t XD = (size_t)MTOK * DMODEL;        // 4,194,304 elements
  char* p = (char*)d_ws;
  int*  flag = (int*)p;       p += 256;
  bf16* pSaB = (bf16*)p;      p += (size_t)NLAYER * 4 * DMODEL * 2;
  bf16* pCaB = (bf16*)p;      p += (size_t)NLAYER * 4 * DMODEL * 2;
  bf16* pLnG = (bf16*)p;      p += (size_t)NLAYER * 3 * DMODEL * 2;
  bf16* pLnB = (bf16*)p;      p += (size_t)NLAYER * 3 * DMODEL * 2;
  bf16* pB1  = (bf16*)p;      p += (size_t)NLAYER * FFDIM * 2;
  bf16* pB2  = (bf16*)p;      p += (size_t)NLAYER * DMODEL * 2;
  p = (char*)d_ws + (1 << 20);                                             // 1MB mark
  bf16* x    = (bf16*)p; p += XD * 2;                                      // 8MB
  bf16* encB = (bf16*)p; p += XD * 2;                                      // 8MB
  bf16* qkv  = (bf16*)p; p += (size_t)MTOK * QKVLD * 2;                    // 24MB
  bf16* ob   = (bf16*)p; p += XD * 2;                                      // 8MB
  bf16* hb   = (bf16*)p; p += XD * 2;                                      // 8MB (unused now)
  bf16* Vt   = (bf16*)p; p += (size_t)BATCH * NHEAD * DHEAD * SEQLEN * 2;  // 8MB
  bf16* Wt   = (bf16*)p; p += (size_t)4 * DMODEL * DMODEL * 2;             // 8MB
  bf16* big  = (bf16*)p; p += (size_t)BATCH * NHEAD * SEQLEN * SEQLEN * 2; // 64MB
  bf16* Sb   = big;
  bf16* ffh  = big;
  (void)hb;
  // fp32 split-K partial buffers (time-share `big`):
  //  - out-proj partials: big[0 .. 32MB)  (Sb dead after PV)
  //  - FFN-down partials: big[32MB .. 64MB)  (ffh occupies [0,32MB))
  float* Pf  = (float*)big;
  float* PfF = (float*)((char*)big + 33554432);
  const long PZ = (long)MTOK * DMODEL;     // elements per fp32 partial

  const long PQ = (long)SEQLEN * QKVLD;    // 1572864: batch stride in qkv buffer
  const long PD = (long)SEQLEN * DMODEL;   // 524288
  const long SS = (long)SEQLEN * SEQLEN;   // 262144
  const long VS = (long)DHEAD * SEQLEN;    // 32768
  const long DD = (long)DMODEL * DMODEL;   // 1048576

  // --- dtype detection + input conversion ---
  kdetect<<<1, 256, 0, stream>>>((const unsigned short*)trg_r, flag);
  int nb = (int)((XD + 255) / 256);
  kcvt<<<nb, 256, 0, stream>>>(trg_r, x,    (long)XD, flag);
  kcvt<<<nb, 256, 0, stream>>>(enc_r, encB, (long)XD, flag);
  kcvt<<<96,  256, 0, stream>>>(sa_b_r, pSaB, (long)NLAYER * 4 * DMODEL, flag);
  kcvt<<<96,  256, 0, stream>>>(ca_b_r, pCaB, (long)NLAYER * 4 * DMODEL, flag);
  kcvt<<<72,  256, 0, stream>>>(ln_g_r, pLnG, (long)NLAYER * 3 * DMODEL, flag);
  kcvt<<<72,  256, 0, stream>>>(ln_b_r, pLnB, (long)NLAYER * 3 * DMODEL, flag);
  kcvt<<<96,  256, 0, stream>>>(b1_r,   pB1,  (long)NLAYER * FFDIM,      flag);
  kcvt<<<24,  256, 0, stream>>>(b2_r,   pB2,  (long)NLAYER * DMODEL,     flag);

  dim3 tb(32, 8, 1);
  for (int l = 0; l < NLAYER; l++) {
    for (int att = 0; att < 2; att++) {
      const void* Wraw = (att == 0) ? sa_w_r : ca_w_r;
      const bf16* Bv   = ((att == 0) ? pSaB : pCaB) + (size_t)l * 4 * DMODEL;
      const int*  mk   = (att == 0) ? mask : nullptr;

      // transpose (+convert) 4 weights [K][N] -> Wt[i][N][K]; q|k|v contiguous
      ktranspose<<<dim3(32, 32, 4), tb, 0, stream>>>(
          Wraw, Wt, DMODEL, DMODEL, DMODEL, (long)l * 4 * DD, 0, DD, 4, DD, flag, 1);
      if (att == 0) {
        // fused QKV: [4096,1024] @ [3072,1024]^T -> qkv[4096,3072]  (192 blocks)
        kgemm256<false, false><<<dim3(16, 12, 1), 512, 0, stream>>>(
            x, Wt, qkv, Bv, 1024, 1024, 1024, QKVLD);
      } else {
        // Q from x (legacy 64x128, 512 blocks); K|V fused from enc (128 blocks)
        kgemm_nt<64,128,2,2,false><<<dim3(64, 8, 1), 256, 0, stream>>>(
            x, Wt, qkv, Bv, 1024, 1024, 1024, QKVLD, 0,0,0,0,0,0, 1, 1.f);
        kgemm256<false, false><<<dim3(16, 8, 1), 512, 0, stream>>>(
            encB, Wt + DD, qkv + 1024, Bv + 1024, 1024, 1024, 1024, QKVLD);
      }
      // S[bh] = (Q_bh @ K_bh^T) / 8  over 128 (b,h) pairs (2048 blocks)
      kgemm_nt<128,128,2,2,false><<<dim3(4, 4, 128), 256, 0, stream>>>(
          qkv, qkv + 1024, Sb, nullptr, 64, QKVLD, QKVLD, 512,
          PQ, 64, PQ, 64, 16 * SS, SS, 16, 0.125f);
      ksoftmax<<<dim3(512, 128), 256, 0, stream>>>(Sb, mk);
      // Vt[bh][d][j] = V[bh][j][d]
      ktranspose<<<dim3(16, 2, 128), tb, 0, stream>>>(
          qkv + 2048, Vt, SEQLEN, DHEAD, QKVLD, 0, PQ, 64, 16, VS, flag, 0);
      // O[bh] = P_bh @ V_bh (512 blocks)
      kgemm_nt<128,64,2,2,false><<<dim3(4, 1, 128), 256, 0, stream>>>(
          Sb, Vt, ob, nullptr, 512, 512, 512, 1024,
          16 * SS, SS, 16 * VS, VS, PD, 64, 16, 1.f);
      // output projection: split-K=2, fp32 partials into Pf (Sb is dead now)
      kgemm256<false, true><<<dim3(16, 4, 2), 512, 0, stream>>>(
          ob, Wt + 3 * DD, Pf, nullptr, 512, 1024, 1024, 1024);
      // x = LN(P0 + P1 + biasO + x)
      kaddln2<<<dim3(MTOK), 256, 0, stream>>>(Pf, Pf + PZ, Bv + 3 * DMODEL, x,
          pLnG + (size_t)(l * 3 + att) * DMODEL, pLnB + (size_t)(l * 3 + att) * DMODEL);
    }

    // ===================== FFN =====================
    ktranspose<<<dim3(32, 128, 1), tb, 0, stream>>>(
        w1_r, Wt, DMODEL, FFDIM, FFDIM, (long)l * DMODEL * FFDIM, 0, 0, 1, 0, flag, 1);
    // FFN up: 4096x4096x1024, ReLU (256 blocks)
    kgemm256<true, false><<<dim3(16, 16, 1), 512, 0, stream>>>(
        x, Wt, ffh, pB1 + (size_t)l * FFDIM, 1024, 1024, 1024, 4096);
    ktranspose<<<dim3(128, 32, 1), tb, 0, stream>>>(
        w2_r, Wt, FFDIM, DMODEL, DMODEL, (long)l * FFDIM * DMODEL, 0, 0, 1, 0, flag, 1);
    // FFN down: split-K=2 (K=2048 each), fp32 partials into upper half of big
    kgemm256<false, true><<<dim3(16, 4, 2), 512, 0, stream>>>(
        ffh, Wt, PfF, nullptr, 2048, 4096, 4096, 1024);
    kaddln2<<<dim3(MTOK), 256, 0, stream>>>(PfF, PfF + PZ, pB2 + (size_t)l * DMODEL, x,
        pLnG + (size_t)(l * 3 + 2) * DMODEL, pLnB + (size_t)(l * 3 + 2) * DMODEL);
  }

  kout<<<nb, 256, 0, stream>>>(x, d_out, (long)XD, flag);
}

// Round 4
// 3259.209 us; speedup vs baseline: 1.0752x; 1.0283x over previous
//
#include <hip/hip_runtime.h>

typedef __bf16 bf16;
typedef __bf16 bf16x8 __attribute__((ext_vector_type(8)));
typedef __bf16 bf16x4 __attribute__((ext_vector_type(4)));
typedef float  f32x4  __attribute__((ext_vector_type(4)));

#define NLAYER 6
#define DMODEL 1024
#define NHEAD  16
#define DHEAD  64
#define FFDIM  4096
#define BATCH  8
#define SEQLEN 512
#define MTOK   (BATCH * SEQLEN)   // 4096 tokens
#define QKVLD  3072               // fused q|k|v row stride

#define GAS(p) ((const __attribute__((address_space(1))) void*)(p))
#define LAS(p) ((__attribute__((address_space(3))) void*)(p))

// ---------------------------------------------------------------------------
// Dtype detection: scan first 64K 16-bit words of trg. fp32 data -> ~128 words
// whose bf16-exponent bits are all-ones; bf16 N(0,1) data -> 0.
// ---------------------------------------------------------------------------
__global__ __launch_bounds__(256) void kdetect(const unsigned short* __restrict__ w,
                                               int* __restrict__ flag)
{
  __shared__ int cnt;
  if (threadIdx.x == 0) cnt = 0;
  __syncthreads();
  int c = 0;
  for (int i = threadIdx.x; i < 65536; i += 256)
    c += (((w[i] >> 7) & 0xFF) == 0xFF);
  atomicAdd(&cnt, c);
  __syncthreads();
  if (threadIdx.x == 0) *flag = (cnt > 16) ? 1 : 0;
}

__global__ __launch_bounds__(256) void kcvt(const void* __restrict__ src,
                                            bf16* __restrict__ dst, long n,
                                            const int* __restrict__ flag)
{
  long i = (long)blockIdx.x * 256 + threadIdx.x;
  if (i >= n) return;
  if (*flag) dst[i] = (bf16)((const float*)src)[i];
  else       dst[i] = ((const bf16*)src)[i];
}

__global__ __launch_bounds__(256) void kout(const bf16* __restrict__ src,
                                            void* __restrict__ dst, long n,
                                            const int* __restrict__ flag)
{
  long i = (long)blockIdx.x * 256 + threadIdx.x;
  if (i >= n) return;
  if (*flag) ((float*)dst)[i] = (float)src[i];
  else       ((bf16*)dst)[i]  = src[i];
}

// ---------------------------------------------------------------------------
// Batched transpose with fused dtype conversion.
// ---------------------------------------------------------------------------
__global__ __launch_bounds__(256) void ktranspose(
    const void* __restrict__ in, bf16* __restrict__ out,
    int R, int C, int ldin, long ebase, long ibs0, long ibs1, int nb1, long obs,
    const int* __restrict__ flag, int mode)
{
  __shared__ bf16 tile[32][33];
  bool f32in = mode && *flag;
  int z = blockIdx.z;
  long base = ebase + (long)(z / nb1) * ibs0 + (long)(z % nb1) * ibs1;
  bf16* dst = out + (long)z * obs;
  int r0 = blockIdx.x * 32, c0 = blockIdx.y * 32;
  int tx = threadIdx.x, ty = threadIdx.y;
  const float* fp = (const float*)in;
  const bf16*  bp = (const bf16*)in;
#pragma unroll
  for (int i = 0; i < 32; i += 8) {
    long idx = base + (long)(r0 + ty + i) * ldin + (c0 + tx);
    tile[ty + i][tx] = f32in ? (bf16)fp[idx] : bp[idx];
  }
  __syncthreads();
#pragma unroll
  for (int i = 0; i < 32; i += 8)
    dst[(long)(c0 + ty + i) * R + (r0 + tx)] = tile[tx][ty + i];
}

// ---------------------------------------------------------------------------
// Legacy batched NT GEMM (m97 structure) — kept for S=QK^T, PV, cross-Q.
// ---------------------------------------------------------------------------
template<int BM, int BN, int WM, int WN, bool RELU>
__global__ __launch_bounds__(256) void kgemm_nt(
    const bf16* __restrict__ A, const bf16* __restrict__ B, bf16* __restrict__ C,
    const bf16* __restrict__ bias, int K, int lda, int ldb, int ldc,
    long aB0, long aB1, long bB0, long bB1, long cB0, long cB1,
    int nb1, float scale)
{
  constexpr int TM = BM / WM, TN = BN / WN;
  constexpr int FM = TM / 16, FN = TN / 16;
  __shared__ __align__(16) bf16 At[BM * 64];
  __shared__ __align__(16) bf16 Bt[BN * 64];

  int z = blockIdx.z, z0 = z / nb1, z1 = z % nb1;
  const bf16* Ab = A + z0 * aB0 + z1 * aB1;
  const bf16* Bb = B + z0 * bB0 + z1 * bB1;
  bf16* Cb = C + z0 * cB0 + z1 * cB1;

  int row0 = blockIdx.x * BM, col0 = blockIdx.y * BN;
  int t = threadIdx.x;
  int lane = t & 63, w = t >> 6;
  int wm = w / WN, wn = w % WN;
  int m16 = lane & 15, quad = lane >> 4;

  f32x4 acc[FM][FN];
#pragma unroll
  for (int i = 0; i < FM; i++)
#pragma unroll
    for (int j = 0; j < FN; j++)
      acc[i][j] = f32x4{0.f, 0.f, 0.f, 0.f};

  int sr = t >> 3, sc = (t & 7) * 8;
  const bf16* ga = Ab + (long)(row0 + sr) * lda + sc;
  const bf16* gb = Bb + (long)(col0 + sr) * ldb + sc;

  for (int k0 = 0; k0 < K; k0 += 64) {
#pragma unroll
    for (int i = 0; i < BM / 32; i++)
      __builtin_amdgcn_global_load_lds(GAS(ga + (long)i * 32 * lda + k0),
                                       LAS(&At[t * 8 + i * 2048]), 16, 0, 0);
#pragma unroll
    for (int i = 0; i < BN / 32; i++)
      __builtin_amdgcn_global_load_lds(GAS(gb + (long)i * 32 * ldb + k0),
                                       LAS(&Bt[t * 8 + i * 2048]), 16, 0, 0);
    __syncthreads();
#pragma unroll
    for (int s = 0; s < 2; s++) {
      bf16x8 af[FM], bfr[FN];
#pragma unroll
      for (int i = 0; i < FM; i++)
        af[i] = *(const bf16x8*)&At[(wm * TM + i * 16 + m16) * 64 + s * 32 + quad * 8];
#pragma unroll
      for (int j = 0; j < FN; j++)
        bfr[j] = *(const bf16x8*)&Bt[(wn * TN + j * 16 + m16) * 64 + s * 32 + quad * 8];
#pragma unroll
      for (int i = 0; i < FM; i++)
#pragma unroll
        for (int j = 0; j < FN; j++)
          acc[i][j] = __builtin_amdgcn_mfma_f32_16x16x32_bf16(af[i], bfr[j], acc[i][j], 0, 0, 0);
    }
    __syncthreads();
  }

#pragma unroll
  for (int j = 0; j < FN; j++) {
    int col = col0 + wn * TN + j * 16 + m16;
    float bv = bias ? (float)bias[col] : 0.f;
#pragma unroll
    for (int i = 0; i < FM; i++) {
      int row = row0 + wm * TM + i * 16 + quad * 4;
#pragma unroll
      for (int r = 0; r < 4; r++) {
        float v = acc[i][j][r] * scale + bv;
        if (RELU) v = fmaxf(v, 0.f);
        Cb[(long)(row + r) * ldc + col] = (bf16)v;
      }
    }
  }
}

// ---------------------------------------------------------------------------
// 256x256 NT GEMM, 8 waves (2Mx4N), BK=64.
// Deep pipeline: A double-buffered (64KB) + B TRIPLE-buffered (96KB) = 160KB.
// qm-major phases per K-tile kt:
//   ph0: acc[0..3] s=0  (reads B s0 -> b0[], A q(2wm) s0)   stage A(kt+1) q0,q2
//   ph1: acc[0..3] s=1  (reads B s1 -> b1[], A q(2wm) s1)   stage A(kt+1) q1,q3  [G vmcnt(6)]
//   ph2: acc[4..7] s=0  (reads A q(2wm+1) s0; b0 reused)    stage B(kt+2) q0,q1
//   ph3: acc[4..7] s=1  (reads A q(2wm+1) s1; b1 reused)    stage B(kt+2) q2,q3  [G vmcnt(6)]
// FIFO bookkeeping (steady state, 8 issues/tile): both gates retire exactly the
// loads needed by the next phase(s), and every gated load is >=3 phases old
// (~1000+ cyc of cover vs ~900 cyc HBM latency). Tails issue CLAMPED dummy
// stages into provably-dead buffers so counts stay uniform (no branchy gates).
// LDS swizzle: logical (r,c) at byte r*128 + ((c*2) ^ ((r&7)<<4)); linear
// global_load_lds dest + inverse-swizzled global source (rule #21).
// ---------------------------------------------------------------------------
template<bool RELU, bool F32OUT>
__global__ __launch_bounds__(512, 2) void kgemm256(
    const bf16* __restrict__ A, const bf16* __restrict__ B, void* __restrict__ Cv,
    const bf16* __restrict__ bias, int K, int lda, int ldb, int ldc)
{
  __shared__ __align__(16) bf16 As[2][256 * 64];   // 32KB x2 = 64KB
  __shared__ __align__(16) bf16 Bs[3][256 * 64];   // 32KB x3 = 96KB -> 160KB

  const int t = threadIdx.x;
  const int lane = t & 63;
  const int w = t >> 6, wm = w >> 2, wn = w & 3;   // 2 x 4 waves
  const int m16 = lane & 15, quad = lane >> 4;

  const long zk = (long)blockIdx.z * K;            // K-split offset
  const int row0 = blockIdx.x * 256, col0 = blockIdx.y * 256;

  // staging: thread t covers row sr = t>>3 (of a 64-row quarter), octet t&7;
  // global source octet XOR-permuted to realize the read-side swizzle.
  const int sr = t >> 3;
  const int so = (((t & 7) ^ (sr & 7)) << 3);
  const bf16* ga = A + zk + (long)(row0 + sr) * lda + so;
  const bf16* gb = B + zk + (long)(col0 + sr) * ldb + so;

  f32x4 acc[8][4];
#pragma unroll
  for (int i = 0; i < 8; i++)
#pragma unroll
    for (int j = 0; j < 4; j++) acc[i][j] = f32x4{0.f, 0.f, 0.f, 0.f};

  const int NT = K / 64;

  // one quarter = 64 rows x 64 cols = 8KB = 1 global_load_lds per thread.
  // tt is clamped for the ADDRESS only; the buffer index keeps the schedule's
  // tt so out-of-range (dummy) stages land in dead buffers.
  auto stageA = [&](int tt, int q) {
    int tc = tt < NT ? tt : NT - 1;
    __builtin_amdgcn_global_load_lds(GAS(ga + (long)tc * 64 + (long)q * 64 * lda),
                                     LAS((char*)&As[tt & 1][0] + t * 16 + q * 8192),
                                     16, 0, 0);
  };
  auto stageB = [&](int tt, int q) {
    int tc = tt < NT ? tt : NT - 1;
    __builtin_amdgcn_global_load_lds(GAS(gb + (long)tc * 64 + (long)q * 64 * ldb),
                                     LAS((char*)&Bs[tt % 3][0] + t * 16 + q * 8192),
                                     16, 0, 0);
  };

  // prologue: B(0), A(0), B(1); gate allows B(1)'s 4 loads to stay in flight.
  stageB(0, 0); stageB(0, 1); stageB(0, 2); stageB(0, 3);
  stageA(0, 0); stageA(0, 2); stageA(0, 1); stageA(0, 3);
  stageB(1, 0); stageB(1, 1); stageB(1, 2); stageB(1, 3);
  asm volatile("s_waitcnt vmcnt(4)" ::: "memory");
  __builtin_amdgcn_s_barrier();

  bf16x8 b0[4], b1[4];   // B frags for s=0 / s=1, live across the whole tile
  for (int kt = 0; kt < NT; kt++) {
    const char* Ab = (const char*)&As[kt & 1][0];
    const char* Bb = (const char*)&Bs[kt % 3][0];

    // ---- ph0: qm=0, s=0 ----
    {
      bf16x8 af[4];
#pragma unroll
      for (int j = 0; j < 4; j++) {
        const int r = wn * 64 + j * 16 + m16;
        b0[j] = *(const bf16x8*)(Bb + r * 128 + ((quad * 16) ^ ((r & 7) << 4)));
      }
#pragma unroll
      for (int i = 0; i < 4; i++) {
        const int r = wm * 128 + i * 16 + m16;
        af[i] = *(const bf16x8*)(Ab + r * 128 + ((quad * 16) ^ ((r & 7) << 4)));
      }
      stageA(kt + 1, 0); stageA(kt + 1, 2);
      __builtin_amdgcn_s_barrier();
      asm volatile("s_waitcnt lgkmcnt(0)" ::: "memory");
      __builtin_amdgcn_sched_barrier(0);
      __builtin_amdgcn_s_setprio(1);
#pragma unroll
      for (int i = 0; i < 4; i++)
#pragma unroll
        for (int j = 0; j < 4; j++)
          acc[i][j] = __builtin_amdgcn_mfma_f32_16x16x32_bf16(af[i], b0[j], acc[i][j], 0, 0, 0);
      __builtin_amdgcn_s_setprio(0);
      __builtin_amdgcn_s_barrier();
    }

    // ---- ph1: qm=0, s=1 ----
    {
      bf16x8 af[4];
#pragma unroll
      for (int j = 0; j < 4; j++) {
        const int r = wn * 64 + j * 16 + m16;
        b1[j] = *(const bf16x8*)(Bb + r * 128 + ((64 + quad * 16) ^ ((r & 7) << 4)));
      }
#pragma unroll
      for (int i = 0; i < 4; i++) {
        const int r = wm * 128 + i * 16 + m16;
        af[i] = *(const bf16x8*)(Ab + r * 128 + ((64 + quad * 16) ^ ((r & 7) << 4)));
      }
      stageA(kt + 1, 1); stageA(kt + 1, 3);
      __builtin_amdgcn_s_barrier();
      asm volatile("s_waitcnt lgkmcnt(0)" ::: "memory");
      __builtin_amdgcn_sched_barrier(0);
      __builtin_amdgcn_s_setprio(1);
#pragma unroll
      for (int i = 0; i < 4; i++)
#pragma unroll
        for (int j = 0; j < 4; j++)
          acc[i][j] = __builtin_amdgcn_mfma_f32_16x16x32_bf16(af[i], b1[j], acc[i][j], 0, 0, 0);
      __builtin_amdgcn_s_setprio(0);
      asm volatile("s_waitcnt vmcnt(6)" ::: "memory");
      __builtin_amdgcn_s_barrier();
    }

    // ---- ph2: qm=1, s=0 (b0 reused) ----
    {
      bf16x8 af[4];
#pragma unroll
      for (int i = 0; i < 4; i++) {
        const int r = wm * 128 + 64 + i * 16 + m16;
        af[i] = *(const bf16x8*)(Ab + r * 128 + ((quad * 16) ^ ((r & 7) << 4)));
      }
      stageB(kt + 2, 0); stageB(kt + 2, 1);
      __builtin_amdgcn_s_barrier();
      asm volatile("s_waitcnt lgkmcnt(0)" ::: "memory");
      __builtin_amdgcn_sched_barrier(0);
      __builtin_amdgcn_s_setprio(1);
#pragma unroll
      for (int i = 0; i < 4; i++)
#pragma unroll
        for (int j = 0; j < 4; j++)
          acc[4 + i][j] = __builtin_amdgcn_mfma_f32_16x16x32_bf16(af[i], b0[j], acc[4 + i][j], 0, 0, 0);
      __builtin_amdgcn_s_setprio(0);
      __builtin_amdgcn_s_barrier();
    }

    // ---- ph3: qm=1, s=1 (b1 reused) ----
    {
      bf16x8 af[4];
#pragma unroll
      for (int i = 0; i < 4; i++) {
        const int r = wm * 128 + 64 + i * 16 + m16;
        af[i] = *(const bf16x8*)(Ab + r * 128 + ((64 + quad * 16) ^ ((r & 7) << 4)));
      }
      stageB(kt + 2, 2); stageB(kt + 2, 3);
      __builtin_amdgcn_s_barrier();
      asm volatile("s_waitcnt lgkmcnt(0)" ::: "memory");
      __builtin_amdgcn_sched_barrier(0);
      __builtin_amdgcn_s_setprio(1);
#pragma unroll
      for (int i = 0; i < 4; i++)
#pragma unroll
        for (int j = 0; j < 4; j++)
          acc[4 + i][j] = __builtin_amdgcn_mfma_f32_16x16x32_bf16(af[i], b1[j], acc[4 + i][j], 0, 0, 0);
      __builtin_amdgcn_s_setprio(0);
      asm volatile("s_waitcnt vmcnt(6)" ::: "memory");
      __builtin_amdgcn_s_barrier();
    }
  }

  // epilogue — C/D layout: col = lane&15, row = (lane>>4)*4 + reg
  if constexpr (F32OUT) {
    float* Cf = (float*)Cv + (long)blockIdx.z * gridDim.x * 256 * ldc;
#pragma unroll
    for (int j = 0; j < 4; j++) {
      const int col = col0 + wn * 64 + j * 16 + m16;
#pragma unroll
      for (int i = 0; i < 8; i++) {
        const int row = row0 + wm * 128 + i * 16 + quad * 4;
#pragma unroll
        for (int r = 0; r < 4; r++)
          Cf[(long)(row + r) * ldc + col] = acc[i][j][r];
      }
    }
  } else {
    bf16* Cb = (bf16*)Cv;
#pragma unroll
    for (int j = 0; j < 4; j++) {
      const int col = col0 + wn * 64 + j * 16 + m16;
      const float bv = (float)bias[col];
#pragma unroll
      for (int i = 0; i < 8; i++) {
        const int row = row0 + wm * 128 + i * 16 + quad * 4;
#pragma unroll
        for (int r = 0; r < 4; r++) {
          float v = acc[i][j][r] + bv;
          if (RELU) v = fmaxf(v, 0.f);
          Cb[(long)(row + r) * ldc + col] = (bf16)v;
        }
      }
    }
  }
}

// ---------------------------------------------------------------------------
// Row softmax over S[bh][q][0:512], optional mask (-10000 where mask==0).
// ---------------------------------------------------------------------------
__global__ __launch_bounds__(256) void ksoftmax(
    bf16* __restrict__ S, const int* __restrict__ mask)
{
  int q = blockIdx.x, bh = blockIdx.y, b = bh >> 4;
  bf16* row = S + ((long)bh * SEQLEN + q) * SEQLEN;
  int t = threadIdx.x;
  float v0 = (float)row[t], v1 = (float)row[t + 256];
  if (mask) {
    const int* mrow = mask + ((long)b * SEQLEN + q) * SEQLEN;
    if (mrow[t] == 0)       v0 = -10000.f;
    if (mrow[t + 256] == 0) v1 = -10000.f;
  }
  float mx = fmaxf(v0, v1);
#pragma unroll
  for (int off = 32; off > 0; off >>= 1) mx = fmaxf(mx, __shfl_down(mx, off));
  __shared__ float r1[4], r2[4];
  if ((t & 63) == 0) r1[t >> 6] = mx;
  __syncthreads();
  mx = fmaxf(fmaxf(r1[0], r1[1]), fmaxf(r1[2], r1[3]));
  float e0 = __expf(v0 - mx), e1 = __expf(v1 - mx);
  float s = e0 + e1;
#pragma unroll
  for (int off = 32; off > 0; off >>= 1) s += __shfl_down(s, off);
  if ((t & 63) == 0) r2[t >> 6] = s;
  __syncthreads();
  float inv = 1.f / (r2[0] + r2[1] + r2[2] + r2[3]);
  row[t]       = (bf16)(e0 * inv);
  row[t + 256] = (bf16)(e1 * inv);
}

// ---------------------------------------------------------------------------
// Fused residual add + LayerNorm: x = LN(h + x) * g + b (fp32 math).
// ---------------------------------------------------------------------------
__global__ __launch_bounds__(256) void kaddln(
    const bf16* __restrict__ h, bf16* __restrict__ x,
    const bf16* __restrict__ g, const bf16* __restrict__ b)
{
  long row = blockIdx.x;
  const bf16* hr = h + row * DMODEL;
  bf16* xr = x + row * DMODEL;
  int t = threadIdx.x;
  bf16x4 hv = *(const bf16x4*)&hr[t * 4];
  bf16x4 xv = *(const bf16x4*)&xr[t * 4];
  float v[4]; float s1 = 0.f, s2 = 0.f;
#pragma unroll
  for (int i = 0; i < 4; i++) {
    v[i] = (float)hv[i] + (float)xv[i];
    s1 += v[i]; s2 += v[i] * v[i];
  }
#pragma unroll
  for (int off = 32; off > 0; off >>= 1) {
    s1 += __shfl_down(s1, off);
    s2 += __shfl_down(s2, off);
  }
  __shared__ float a1[4], a2[4];
  if ((t & 63) == 0) { a1[t >> 6] = s1; a2[t >> 6] = s2; }
  __syncthreads();
  s1 = a1[0] + a1[1] + a1[2] + a1[3];
  s2 = a2[0] + a2[1] + a2[2] + a2[3];
  float mean = s1 * (1.f / DMODEL);
  float var  = s2 * (1.f / DMODEL) - mean * mean;
  float rstd = rsqrtf(var + 1e-12f);
  bf16x4 gv = *(const bf16x4*)&g[t * 4];
  bf16x4 bv = *(const bf16x4*)&b[t * 4];
  bf16x4 o;
#pragma unroll
  for (int i = 0; i < 4; i++)
    o[i] = (bf16)(((v[i] - mean) * rstd) * (float)gv[i] + (float)bv[i]);
  *(bf16x4*)&xr[t * 4] = o;
}

// ---------------------------------------------------------------------------
// Split-K reduce + bias + residual add + LayerNorm:
// x = LN(h0 + h1 + bias + x) * g + b  (h0,h1 fp32 partials from kgemm256).
// ---------------------------------------------------------------------------
__global__ __launch_bounds__(256) void kaddln2(
    const float* __restrict__ h0, const float* __restrict__ h1,
    const bf16* __restrict__ bias, bf16* __restrict__ x,
    const bf16* __restrict__ g, const bf16* __restrict__ b)
{
  long row = blockIdx.x;
  const float* h0r = h0 + row * DMODEL;
  const float* h1r = h1 + row * DMODEL;
  bf16* xr = x + row * DMODEL;
  int t = threadIdx.x;
  f32x4 a0 = *(const f32x4*)&h0r[t * 4];
  f32x4 a1 = *(const f32x4*)&h1r[t * 4];
  bf16x4 xv = *(const bf16x4*)&xr[t * 4];
  bf16x4 bi = *(const bf16x4*)&bias[t * 4];
  float v[4]; float s1 = 0.f, s2 = 0.f;
#pragma unroll
  for (int i = 0; i < 4; i++) {
    v[i] = a0[i] + a1[i] + (float)bi[i] + (float)xv[i];
    s1 += v[i]; s2 += v[i] * v[i];
  }
#pragma unroll
  for (int off = 32; off > 0; off >>= 1) {
    s1 += __shfl_down(s1, off);
    s2 += __shfl_down(s2, off);
  }
  __shared__ float r1[4], r2[4];
  if ((t & 63) == 0) { r1[t >> 6] = s1; r2[t >> 6] = s2; }
  __syncthreads();
  s1 = r1[0] + r1[1] + r1[2] + r1[3];
  s2 = r2[0] + r2[1] + r2[2] + r2[3];
  float mean = s1 * (1.f / DMODEL);
  float var  = s2 * (1.f / DMODEL) - mean * mean;
  float rstd = rsqrtf(var + 1e-12f);
  bf16x4 gv = *(const bf16x4*)&g[t * 4];
  bf16x4 bv = *(const bf16x4*)&b[t * 4];
  bf16x4 o;
#pragma unroll
  for (int i = 0; i < 4; i++)
    o[i] = (bf16)(((v[i] - mean) * rstd) * (float)gv[i] + (float)bv[i]);
  *(bf16x4*)&xr[t * 4] = o;
}

// ---------------------------------------------------------------------------
extern "C" void kernel_launch(void* const* d_in, const int* in_sizes, int n_in,
                              void* d_out, int out_size, void* d_ws, size_t ws_size,
                              hipStream_t stream)
{
  (void)in_sizes; (void)n_in; (void)out_size; (void)ws_size;
  const void* trg_r  = d_in[0];
  const void* enc_r  = d_in[1];
  const int*  mask   = (const int*)d_in[2];
  const void* sa_w_r = d_in[3];
  const void* sa_b_r = d_in[4];
  const void* ca_w_r = d_in[5];
  const void* ca_b_r = d_in[6];
  const void* ln_g_r = d_in[7];
  const void* ln_b_r = d_in[8];
  const void* w1_r   = d_in[9];
  const void* b1_r   = d_in[10];
  const void* w2_r   = d_in[11];
  const void* b2_r   = d_in[12];

  const size_t XD = (size_t)MTOK * DMODEL;        // 4,194,304 elements
  char* p = (char*)d_ws;
  int*  flag = (int*)p;       p += 256;
  bf16* pSaB = (bf16*)p;      p += (size_t)NLAYER * 4 * DMODEL * 2;
  bf16* pCaB = (bf16*)p;      p += (size_t)NLAYER * 4 * DMODEL * 2;
  bf16* pLnG = (bf16*)p;      p += (size_t)NLAYER * 3 * DMODEL * 2;
  bf16* pLnB = (bf16*)p;      p += (size_t)NLAYER * 3 * DMODEL * 2;
  bf16* pB1  = (bf16*)p;      p += (size_t)NLAYER * FFDIM * 2;
  bf16* pB2  = (bf16*)p;      p += (size_t)NLAYER * DMODEL * 2;
  p = (char*)d_ws + (1 << 20);                                             // 1MB mark
  bf16* x    = (bf16*)p; p += XD * 2;                                      // 8MB
  bf16* encB = (bf16*)p; p += XD * 2;                                      // 8MB
  bf16* qkv  = (bf16*)p; p += (size_t)MTOK * QKVLD * 2;                    // 24MB
  bf16* ob   = (bf16*)p; p += XD * 2;                                      // 8MB
  bf16* hb   = (bf16*)p; p += XD * 2;                                      // 8MB (unused now)
  bf16* Vt   = (bf16*)p; p += (size_t)BATCH * NHEAD * DHEAD * SEQLEN * 2;  // 8MB
  bf16* Wt   = (bf16*)p; p += (size_t)4 * DMODEL * DMODEL * 2;             // 8MB
  bf16* big  = (bf16*)p; p += (size_t)BATCH * NHEAD * SEQLEN * SEQLEN * 2; // 64MB
  bf16* Sb   = big;
  bf16* ffh  = big;
  (void)hb;
  // fp32 split-K partial buffers (time-share `big`):
  //  - out-proj partials: big[0 .. 32MB)  (Sb dead after PV)
  //  - FFN-down partials: big[32MB .. 64MB)  (ffh occupies [0,32MB))
  float* Pf  = (float*)big;
  float* PfF = (float*)((char*)big + 33554432);
  const long PZ = (long)MTOK * DMODEL;     // elements per fp32 partial

  const long PQ = (long)SEQLEN * QKVLD;    // 1572864: batch stride in qkv buffer
  const long PD = (long)SEQLEN * DMODEL;   // 524288
  const long SS = (long)SEQLEN * SEQLEN;   // 262144
  const long VS = (long)DHEAD * SEQLEN;    // 32768
  const long DD = (long)DMODEL * DMODEL;   // 1048576

  // --- dtype detection + input conversion ---
  kdetect<<<1, 256, 0, stream>>>((const unsigned short*)trg_r, flag);
  int nb = (int)((XD + 255) / 256);
  kcvt<<<nb, 256, 0, stream>>>(trg_r, x,    (long)XD, flag);
  kcvt<<<nb, 256, 0, stream>>>(enc_r, encB, (long)XD, flag);
  kcvt<<<96,  256, 0, stream>>>(sa_b_r, pSaB, (long)NLAYER * 4 * DMODEL, flag);
  kcvt<<<96,  256, 0, stream>>>(ca_b_r, pCaB, (long)NLAYER * 4 * DMODEL, flag);
  kcvt<<<72,  256, 0, stream>>>(ln_g_r, pLnG, (long)NLAYER * 3 * DMODEL, flag);
  kcvt<<<72,  256, 0, stream>>>(ln_b_r, pLnB, (long)NLAYER * 3 * DMODEL, flag);
  kcvt<<<96,  256, 0, stream>>>(b1_r,   pB1,  (long)NLAYER * FFDIM,      flag);
  kcvt<<<24,  256, 0, stream>>>(b2_r,   pB2,  (long)NLAYER * DMODEL,     flag);

  dim3 tb(32, 8, 1);
  for (int l = 0; l < NLAYER; l++) {
    for (int att = 0; att < 2; att++) {
      const void* Wraw = (att == 0) ? sa_w_r : ca_w_r;
      const bf16* Bv   = ((att == 0) ? pSaB : pCaB) + (size_t)l * 4 * DMODEL;
      const int*  mk   = (att == 0) ? mask : nullptr;

      // transpose (+convert) 4 weights [K][N] -> Wt[i][N][K]; q|k|v contiguous
      ktranspose<<<dim3(32, 32, 4), tb, 0, stream>>>(
          Wraw, Wt, DMODEL, DMODEL, DMODEL, (long)l * 4 * DD, 0, DD, 4, DD, flag, 1);
      if (att == 0) {
        // fused QKV: [4096,1024] @ [3072,1024]^T -> qkv[4096,3072]  (192 blocks)
        kgemm256<false, false><<<dim3(16, 12, 1), 512, 0, stream>>>(
            x, Wt, qkv, Bv, 1024, 1024, 1024, QKVLD);
      } else {
        // Q from x (legacy 64x128, 512 blocks); K|V fused from enc (128 blocks)
        kgemm_nt<64,128,2,2,false><<<dim3(64, 8, 1), 256, 0, stream>>>(
            x, Wt, qkv, Bv, 1024, 1024, 1024, QKVLD, 0,0,0,0,0,0, 1, 1.f);
        kgemm256<false, false><<<dim3(16, 8, 1), 512, 0, stream>>>(
            encB, Wt + DD, qkv + 1024, Bv + 1024, 1024, 1024, 1024, QKVLD);
      }
      // S[bh] = (Q_bh @ K_bh^T) / 8  over 128 (b,h) pairs (2048 blocks)
      kgemm_nt<128,128,2,2,false><<<dim3(4, 4, 128), 256, 0, stream>>>(
          qkv, qkv + 1024, Sb, nullptr, 64, QKVLD, QKVLD, 512,
          PQ, 64, PQ, 64, 16 * SS, SS, 16, 0.125f);
      ksoftmax<<<dim3(512, 128), 256, 0, stream>>>(Sb, mk);
      // Vt[bh][d][j] = V[bh][j][d]
      ktranspose<<<dim3(16, 2, 128), tb, 0, stream>>>(
          qkv + 2048, Vt, SEQLEN, DHEAD, QKVLD, 0, PQ, 64, 16, VS, flag, 0);
      // O[bh] = P_bh @ V_bh (512 blocks)
      kgemm_nt<128,64,2,2,false><<<dim3(4, 1, 128), 256, 0, stream>>>(
          Sb, Vt, ob, nullptr, 512, 512, 512, 1024,
          16 * SS, SS, 16 * VS, VS, PD, 64, 16, 1.f);
      // output projection: split-K=2, fp32 partials into Pf (Sb is dead now)
      kgemm256<false, true><<<dim3(16, 4, 2), 512, 0, stream>>>(
          ob, Wt + 3 * DD, Pf, nullptr, 512, 1024, 1024, 1024);
      // x = LN(P0 + P1 + biasO + x)
      kaddln2<<<dim3(MTOK), 256, 0, stream>>>(Pf, Pf + PZ, Bv + 3 * DMODEL, x,
          pLnG + (size_t)(l * 3 + att) * DMODEL, pLnB + (size_t)(l * 3 + att) * DMODEL);
    }

    // ===================== FFN =====================
    ktranspose<<<dim3(32, 128, 1), tb, 0, stream>>>(
        w1_r, Wt, DMODEL, FFDIM, FFDIM, (long)l * DMODEL * FFDIM, 0, 0, 1, 0, flag, 1);
    // FFN up: 4096x4096x1024, ReLU (256 blocks)
    kgemm256<true, false><<<dim3(16, 16, 1), 512, 0, stream>>>(
        x, Wt, ffh, pB1 + (size_t)l * FFDIM, 1024, 1024, 1024, 4096);
    ktranspose<<<dim3(128, 32, 1), tb, 0, stream>>>(
        w2_r, Wt, FFDIM, DMODEL, DMODEL, (long)l * FFDIM * DMODEL, 0, 0, 1, 0, flag, 1);
    // FFN down: split-K=2 (K=2048 each), fp32 partials into upper half of big
    kgemm256<false, true><<<dim3(16, 4, 2), 512, 0, stream>>>(
        ffh, Wt, PfF, nullptr, 2048, 4096, 4096, 1024);
    kaddln2<<<dim3(MTOK), 256, 0, stream>>>(PfF, PfF + PZ, pB2 + (size_t)l * DMODEL, x,
        pLnG + (size_t)(l * 3 + 2) * DMODEL, pLnB + (size_t)(l * 3 + 2) * DMODEL);
  }

  kout<<<nb, 256, 0, stream>>>(x, d_out, (long)XD, flag);
}